// Round 11
// baseline (141.397 us; speedup 1.0000x reference)
//
#include <hip/hip_runtime.h>

typedef unsigned char u8;
typedef unsigned short u16;
typedef unsigned int u32;
typedef unsigned long long u64;
typedef long long i64;
typedef __attribute__((ext_vector_type(16))) float floatx16;

#define BN 8192
#define DIM 256
#define NSPLIT 8
#define KPS (BN / NSPLIT)   // 1024 keys per split
#define BKN 64              // keys per iter (2 x 32-key subtiles, one barrier)
#define NIT (KPS / BKN)     // 16 iters

__device__ __forceinline__ u16 f2bf(float x) {
    u32 u = __builtin_bit_cast(u32, x);
    u = (u + 0x7fffu + ((u >> 16) & 1u)) >> 16;
    return (u16)u;
}
__device__ __forceinline__ float bf2f(u16 h) {
    return __builtin_bit_cast(float, (u32)h << 16);
}
__device__ __forceinline__ u64 pack4bf(float a, float b, float c, float d) {
    return (u64)f2bf(a) | ((u64)f2bf(b) << 16) | ((u64)f2bf(c) << 32) | ((u64)f2bf(d) << 48);
}
__device__ __forceinline__ u32 pk_fp8(float a, float b, float c, float d) {
    int v = __builtin_amdgcn_cvt_pk_fp8_f32(a, b, 0, false);
    v = __builtin_amdgcn_cvt_pk_fp8_f32(c, d, v, true);
    return (u32)v;
}
__device__ __forceinline__ void gl_lds16(const void* g, void* l) {
    __builtin_amdgcn_global_load_lds(
        (const __attribute__((address_space(1))) u32*)g,
        (__attribute__((address_space(3))) u32*)l, 16, 0, 0);
}

// ---------------- kernel 1: row l2-norm -> fp8 fb (row-major) + fp8 fv (V^T tile images) ----
__global__ __launch_bounds__(256) void k_prep(const float* __restrict__ in,
                                              u8* __restrict__ fb, u8* __restrict__ fv) {
    __shared__ u16 t[32 * 260];
    const int tid = threadIdx.x;
    const int wave = tid >> 6, lane = tid & 63;
    const int kb = blockIdx.x, r0 = kb * 32;
    #pragma unroll
    for (int i = 0; i < 8; ++i) {
        const int rl = wave * 8 + i;
        const float4 v = *(const float4*)(in + (size_t)(r0 + rl) * DIM + lane * 4);
        float ss = v.x * v.x + v.y * v.y + v.z * v.z + v.w * v.w;
        #pragma unroll
        for (int off = 1; off < 64; off <<= 1) ss += __shfl_xor(ss, off, 64);
        const float inv = 1.0f / fmaxf(sqrtf(ss), 1e-12f);
        const float n0 = v.x * inv, n1 = v.y * inv, n2 = v.z * inv, n3 = v.w * inv;
        *(u32*)(fb + (size_t)(r0 + rl) * DIM + lane * 4) = pk_fp8(n0, n1, n2, n3);
        *(u64*)(&t[rl * 260 + lane * 4]) = pack4bf(n0, n1, n2, n3);
    }
    __syncthreads();
    #pragma unroll
    for (int i = 0; i < 4; ++i) {
        const int S = i * 256 + tid;              // 8-byte slot index 0..1023
        const int d = S >> 2;
        const int c = ((S & 3) - (d >> 2)) & 3;   // key octet
        float f[8];
        #pragma unroll
        for (int j = 0; j < 8; ++j) f[j] = bf2f(t[(8 * c + j) * 260 + d]);
        const u32 lo = pk_fp8(f[0], f[1], f[2], f[3]);
        const u32 hi = pk_fp8(f[4], f[5], f[6], f[7]);
        *(u64*)(fv + (size_t)kb * 8192 + S * 8) = ((u64)hi << 32) | lo;
    }
}

// ---------------- kernel 2: fp8 flash attention, anti-phased subtiles ----------------
// 512 blocks x 256 thr (4 waves, q=32/wave), 2 waves/SIMD + 2 blocks/CU.
// BKN=64 staged per barrier; waves 0,2 process sub0->sub1, waves 1,3 sub1->sub0,
// so at any instant ~half the waves feed the (per-CU) matrix pipe while the other
// half run exp/pack on VALU — breaking the serial phase-lock measured in R10.
__global__ __launch_bounds__(256, 2) void k_flash(
        const u8* __restrict__ fb, const u8* __restrict__ fv,
        u16* __restrict__ Opart, float* __restrict__ lpart) {
    __shared__ u8 tileK[2][16384];   // 64 keys x 256 d fp8, chunk-swizzled per 32-key half
    __shared__ u8 tileV[2][16384];   // two pre-swizzled 8KB V^T images

    const int tid = threadIdx.x;
    const int wave = tid >> 6, lane = tid & 63;
    const int c31 = lane & 31, g1 = lane >> 5;
    const int split = blockIdx.x & (NSPLIT - 1);
    const int qblk = blockIdx.x >> 3;
    const int q0 = qblk * 128 + wave * 32;
    const int key0 = split * KPS;
    const int sA = wave & 1, sB = sA ^ 1;   // anti-phased subtile order

    // Q B-frags (fp8, loop-invariant)
    i64 qf[16];
    #pragma unroll
    for (int kc = 0; kc < 16; ++kc)
        qf[kc] = *(const i64*)(fb + (size_t)(q0 + c31) * DIM + kc * 16 + g1 * 8);

    floatx16 o[8];
    #pragma unroll
    for (int i = 0; i < 8; ++i)
        #pragma unroll
        for (int r = 0; r < 16; ++r) o[i][r] = 0.f;
    float lsum = 0.f;

    int offK[4];
    #pragma unroll
    for (int i = 0; i < 4; ++i) {
        const int S = wave * 256 + i * 64 + lane;
        const int r = S >> 4, s = S & 15;
        const int c = (s & 8) | ((s ^ r) & 7);
        offK[i] = r * 256 + c * 16;
    }
    const u8* gK = fb + (size_t)key0 * DIM;
    const u8* gV = fv + (size_t)(key0 >> 5) * 8192;

    auto stage = [&](int s, int b) {
        const size_t oo = (size_t)s * 16384;
        u8* lK = &tileK[b][0] + wave * 4096;
        u8* lV = &tileV[b][0] + wave * 4096;
        #pragma unroll
        for (int i = 0; i < 4; ++i) gl_lds16(gK + oo + offK[i], lK + i * 1024);
        #pragma unroll
        for (int i = 0; i < 4; ++i)
            gl_lds16(gV + oo + wave * 4096 + i * 1024 + lane * 16, lV + i * 1024);
    };

    // per-subtile helpers (operate on registers, addresses differ only by sub*8192)
    auto qk = [&](const u8* tk, floatx16& s) {
        #pragma unroll
        for (int h = 0; h < 2; ++h) {
            i64 kf[8];
            #pragma unroll
            for (int j = 0; j < 8; ++j) {
                const int kc = h * 8 + j;
                const int sw = (kc & 8) | ((kc ^ c31) & 7);
                kf[j] = *(const i64*)(tk + c31 * 256 + sw * 16 + g1 * 8);
            }
            #pragma unroll
            for (int j = 0; j < 8; ++j)
                s = __builtin_amdgcn_mfma_f32_32x32x16_fp8_fp8(kf[j], qf[h * 8 + j], s, 0, 0, 0);
        }
    };
    auto softmax = [&](const floatx16& s, i64& A0, i64& A1) {
        float e[16];
        #pragma unroll
        for (int r = 0; r < 16; ++r) { e[r] = __expf(s[r]); lsum += e[r]; }
        u32 p[4];
        #pragma unroll
        for (int rr = 0; rr < 4; ++rr)
            p[rr] = pk_fp8(e[4 * rr], e[4 * rr + 1], e[4 * rr + 2], e[4 * rr + 3]);
        const u32 x0 = (u32)__shfl_xor((int)(g1 ? p[0] : p[1]), 32, 64);
        const u32 x1 = (u32)__shfl_xor((int)(g1 ? p[2] : p[3]), 32, 64);
        A0 = g1 ? (i64)(((u64)p[1] << 32) | x0) : (i64)(((u64)x0 << 32) | p[0]);
        A1 = g1 ? (i64)(((u64)p[3] << 32) | x1) : (i64)(((u64)x1 << 32) | p[2]);
    };
    auto pv = [&](const u8* tv, i64 A0, i64 A1) {
        #pragma unroll
        for (int kc2 = 0; kc2 < 2; ++kc2) {
            const int cc = kc2 * 2 + g1;
            const int csw = (cc + (c31 >> 2)) & 3;
            i64 vf[8];
            #pragma unroll
            for (int ds = 0; ds < 8; ++ds)
                vf[ds] = *(const i64*)(tv + ((ds * 32 + c31) * 4 + csw) * 8);
            const i64 pa = kc2 ? A1 : A0;
            #pragma unroll
            for (int ds = 0; ds < 8; ++ds)
                o[ds] = __builtin_amdgcn_mfma_f32_32x32x16_fp8_fp8(pa, vf[ds], o[ds], 0, 0, 0);
        }
    };

    stage(0, 0);
    for (int it = 0; it < NIT; ++it) {
        const int b = it & 1;
        __syncthreads();                   // drains DMA(it), issued one iter ago
        if (it + 1 < NIT) stage(it + 1, b ^ 1);

        const u8* tkA = &tileK[b][0] + sA * 8192;
        const u8* tvA = &tileV[b][0] + sA * 8192;
        const u8* tkB = &tileK[b][0] + sB * 8192;
        const u8* tvB = &tileV[b][0] + sB * 8192;

        // interleaved pipeline: QK(A) | exp(A) | QK(B) | PV(A) | exp(B) | PV(B)
        floatx16 s0, s1;
        #pragma unroll
        for (int r = 0; r < 16; ++r) { s0[r] = 0.f; s1[r] = 0.f; }
        i64 A0, A1, B0, B1;
        qk(tkA, s0);
        softmax(s0, A0, A1);
        qk(tkB, s1);
        pv(tvA, A0, A1);
        softmax(s1, B0, B1);
        pv(tvB, B0, B1);
    }

    // ---- epilogue: bf16 partial O + fp32 partial l ----
    u16* ob = Opart + ((size_t)split * BN + q0) * DIM;
    #pragma unroll
    for (int ds = 0; ds < 8; ++ds) {
        #pragma unroll
        for (int r = 0; r < 16; ++r) {
            const int ql = (r & 3) + 8 * (r >> 2) + 4 * g1;
            ob[(size_t)ql * DIM + ds * 32 + c31] = f2bf(o[ds][r]);
        }
    }
    lsum += __shfl_xor(lsum, 32, 64);
    if (g1 == 0) lpart[(size_t)split * BN + q0 + c31] = lsum;
}

// ---------------- kernel 3: merge splits, blend, final l2-normalize ----------------
__global__ __launch_bounds__(256) void k_combine(
        const float* __restrict__ feats, const u16* __restrict__ Opart,
        const float* __restrict__ lpart, float* __restrict__ out) {
    const int row = blockIdx.x * 4 + (threadIdx.x >> 6);
    const int lane = threadIdx.x & 63;

    float L = 0.f;
    #pragma unroll
    for (int s = 0; s < NSPLIT; ++s) L += lpart[(size_t)s * BN + row];

    float a0 = 0.f, a1 = 0.f, a2 = 0.f, a3 = 0.f;
    #pragma unroll
    for (int s = 0; s < NSPLIT; ++s) {
        const ushort4 o = *(const ushort4*)(Opart + ((size_t)s * BN + row) * DIM + lane * 4);
        a0 += bf2f(o.x); a1 += bf2f(o.y); a2 += bf2f(o.z); a3 += bf2f(o.w);
    }
    const float invL = 1.0f / L;

    const float4 v = *(const float4*)(feats + (size_t)row * DIM + lane * 4);
    float ss = v.x * v.x + v.y * v.y + v.z * v.z + v.w * v.w;
    #pragma unroll
    for (int off = 1; off < 64; off <<= 1) ss += __shfl_xor(ss, off, 64);
    const float invf = 1.0f / fmaxf(sqrtf(ss), 1e-12f);

    const float yx = 0.8f * v.x * invf + 0.2f * a0 * invL;
    const float yy = 0.8f * v.y * invf + 0.2f * a1 * invL;
    const float yz = 0.8f * v.z * invf + 0.2f * a2 * invL;
    const float yw = 0.8f * v.w * invf + 0.2f * a3 * invL;

    float s2 = yx * yx + yy * yy + yz * yz + yw * yw;
    #pragma unroll
    for (int off = 1; off < 64; off <<= 1) s2 += __shfl_xor(s2, off, 64);
    const float invn = 1.0f / fmaxf(sqrtf(s2), 1e-12f);

    float4 o; o.x = yx * invn; o.y = yy * invn; o.z = yz * invn; o.w = yw * invn;
    *(float4*)(out + (size_t)row * DIM + lane * 4) = o;
}

// ---------------- launcher ----------------
extern "C" void kernel_launch(void* const* d_in, const int* in_sizes, int n_in,
                              void* d_out, int out_size, void* d_ws, size_t ws_size,
                              hipStream_t stream) {
    const float* feats = (const float*)d_in[0];
    float* out = (float*)d_out;
    char* ws = (char*)d_ws;

    // ws: fb fp8 2MB | fv fp8 2MB | Opart bf16 32MB | lpart fp32 256KB
    u8* fb = (u8*)ws;
    u8* fv = (u8*)(ws + (size_t)BN * DIM);
    u16* Op = (u16*)(ws + (size_t)BN * DIM * 2);
    float* lp = (float*)(ws + (size_t)BN * DIM * 2 + (size_t)NSPLIT * BN * DIM * 2);

    k_prep<<<BN / 32, 256, 0, stream>>>(feats, fb, fv);
    k_flash<<<(BN / 128) * NSPLIT, 256, 0, stream>>>(fb, fv, Op, lp);
    k_combine<<<BN / 4, 256, 0, stream>>>(feats, Op, lp, out);
}

// Round 12
// 131.390 us; speedup vs baseline: 1.0762x; 1.0762x over previous
//
#include <hip/hip_runtime.h>

typedef unsigned char u8;
typedef unsigned short u16;
typedef unsigned int u32;
typedef unsigned long long u64;
typedef long long i64;
typedef __attribute__((ext_vector_type(16))) float floatx16;

#define BN 8192
#define DIM 256
#define NSPLIT 8
#define KPS (BN / NSPLIT)   // 1024 keys per split
#define BKN 32              // keys per iter
#define NIT (KPS / BKN)     // 32 iters

__device__ __forceinline__ u16 f2bf(float x) {
    u32 u = __builtin_bit_cast(u32, x);
    u = (u + 0x7fffu + ((u >> 16) & 1u)) >> 16;
    return (u16)u;
}
__device__ __forceinline__ float bf2f(u16 h) {
    return __builtin_bit_cast(float, (u32)h << 16);
}
__device__ __forceinline__ u64 pack4bf(float a, float b, float c, float d) {
    return (u64)f2bf(a) | ((u64)f2bf(b) << 16) | ((u64)f2bf(c) << 32) | ((u64)f2bf(d) << 48);
}
__device__ __forceinline__ u32 pk_fp8(float a, float b, float c, float d) {
    int v = __builtin_amdgcn_cvt_pk_fp8_f32(a, b, 0, false);
    v = __builtin_amdgcn_cvt_pk_fp8_f32(c, d, v, true);
    return (u32)v;
}
__device__ __forceinline__ void gl_lds16(const void* g, void* l) {
    __builtin_amdgcn_global_load_lds(
        (const __attribute__((address_space(1))) u32*)g,
        (__attribute__((address_space(3))) u32*)l, 16, 0, 0);
}
#define MFMA8(A, B, C) __builtin_amdgcn_mfma_f32_32x32x16_fp8_fp8((A), (B), (C), 0, 0, 0)

// ---------------- kernel 1: row l2-norm -> fp8 fb (row-major) + fp8 fv (V^T tile images) ----
__global__ __launch_bounds__(256) void k_prep(const float* __restrict__ in,
                                              u8* __restrict__ fb, u8* __restrict__ fv) {
    __shared__ u16 t[32 * 260];
    const int tid = threadIdx.x;
    const int wave = tid >> 6, lane = tid & 63;
    const int kb = blockIdx.x, r0 = kb * 32;
    #pragma unroll
    for (int i = 0; i < 8; ++i) {
        const int rl = wave * 8 + i;
        const float4 v = *(const float4*)(in + (size_t)(r0 + rl) * DIM + lane * 4);
        float ss = v.x * v.x + v.y * v.y + v.z * v.z + v.w * v.w;
        #pragma unroll
        for (int off = 1; off < 64; off <<= 1) ss += __shfl_xor(ss, off, 64);
        const float inv = 1.0f / fmaxf(sqrtf(ss), 1e-12f);
        const float n0 = v.x * inv, n1 = v.y * inv, n2 = v.z * inv, n3 = v.w * inv;
        *(u32*)(fb + (size_t)(r0 + rl) * DIM + lane * 4) = pk_fp8(n0, n1, n2, n3);
        *(u64*)(&t[rl * 260 + lane * 4]) = pack4bf(n0, n1, n2, n3);
    }
    __syncthreads();
    #pragma unroll
    for (int i = 0; i < 4; ++i) {
        const int S = i * 256 + tid;              // 8-byte slot index 0..1023
        const int d = S >> 2;
        const int c = ((S & 3) - (d >> 2)) & 3;   // key octet
        float f[8];
        #pragma unroll
        for (int j = 0; j < 8; ++j) f[j] = bf2f(t[(8 * c + j) * 260 + d]);
        const u32 lo = pk_fp8(f[0], f[1], f[2], f[3]);
        const u32 hi = pk_fp8(f[4], f[5], f[6], f[7]);
        *(u64*)(fv + (size_t)kb * 8192 + S * 8) = ((u64)hi << 32) | lo;
    }
}

// ---------------- kernel 2: fp8 flash attention, pipe-interleaved ----------------
// R8 config (512 blocks x 256 thr, q=32/wave, 2 waves/SIMD + 2 blocks/CU) with:
//  * kf/vf LDS reads in ds_read2_b64-formable pairs (qf index permuted by c31&1 so
//    register order matches the swizzled pair order for free; sum order irrelevant)
//  * exp/pack VALU interleaved between PV MFMAs; K-frag loads between QK MFMAs —
//    in-order issue then feeds matrix, VALU and LDS pipes simultaneously (R8-R11
//    ran them serially: 69k+57k+40k cyc/CU ~= the 162k wall).
__global__ __launch_bounds__(256, 2) void k_flash(
        const u8* __restrict__ fb, const u8* __restrict__ fv,
        u16* __restrict__ Opart, float* __restrict__ lpart) {
    __shared__ u8 tileK[2][8192];   // key-major fp8, chunk-swizzled (16B chunks)
    __shared__ u8 tileV[2][8192];   // pre-swizzled V^T fp8 image

    const int tid = threadIdx.x;
    const int wave = tid >> 6, lane = tid & 63;
    const int c31 = lane & 31, g1 = lane >> 5;
    const int split = blockIdx.x & (NSPLIT - 1);
    const int qblk = blockIdx.x >> 3;
    const int q0 = qblk * 128 + wave * 32;
    const int key0 = split * KPS;

    // Q B-frags, pair-permuted: qf[2m+j] holds the fragment for kc = 2m + (j ^ (c31&1))
    // so it pairs with the LDS low/high register order of the kf read2 pairs.
    i64 qf[16];
    #pragma unroll
    for (int kc = 0; kc < 16; ++kc) {
        const int kcl = (kc & ~1) | ((kc ^ c31) & 1);
        qf[kc] = *(const i64*)(fb + (size_t)(q0 + c31) * DIM + kcl * 16 + g1 * 8);
    }

    floatx16 o[8];
    #pragma unroll
    for (int i = 0; i < 8; ++i)
        #pragma unroll
        for (int r = 0; r < 16; ++r) o[i][r] = 0.f;
    float lsum = 0.f;

    int offK[2];
    #pragma unroll
    for (int i = 0; i < 2; ++i) {
        const int S = wave * 128 + i * 64 + lane;   // 16B slot 0..511
        const int r = S >> 4, s = S & 15;
        const int c = (s & 8) | ((s ^ r) & 7);
        offK[i] = r * 256 + c * 16;
    }
    const u8* gK = fb + (size_t)key0 * DIM;
    const u8* gV = fv + (size_t)(key0 >> 5) * 8192;

    auto stage = [&](int s, int b) {
        const size_t oo = (size_t)s * 8192;
        u8* lK = &tileK[b][0] + wave * 2048;
        u8* lV = &tileV[b][0] + wave * 2048;
        #pragma unroll
        for (int i = 0; i < 2; ++i) gl_lds16(gK + oo + offK[i], lK + i * 1024);
        #pragma unroll
        for (int i = 0; i < 2; ++i)
            gl_lds16(gV + oo + wave * 2048 + i * 1024 + lane * 16, lV + i * 1024);
    };

    const int cswA = (g1 + (c31 >> 2)) & 3;          // V chunk swizzle, kc2=0
    const int cswB = (2 + g1 + (c31 >> 2)) & 3;      // kc2=1
    const int kbase = c31 * 256 + g1 * 8;

    stage(0, 0);
    for (int it = 0; it < NIT; ++it) {
        const int b = it & 1;
        __syncthreads();                   // drains DMA(it), issued one iter ago
        if (it + 1 < NIT) stage(it + 1, b ^ 1);

        const u8* tk = &tileK[b][0];
        const u8* tv = &tileV[b][0];

        floatx16 s;
        #pragma unroll
        for (int r = 0; r < 16; ++r) s[r] = 0.f;

        // ---- QK group 1 (kc 0..7): 4 kf read2-pairs + vfa loads overlapped ----
        i64 kf[8], vfa[8];
        #pragma unroll
        for (int m = 0; m < 4; ++m) {
            const int cl = ((2 * m) & 8) | (((2 * m) & 6) ^ (c31 & 6));
            const u8* ba = tk + kbase + cl * 16;
            kf[2 * m] = *(const i64*)(ba);
            kf[2 * m + 1] = *(const i64*)(ba + 16);
        }
        #pragma unroll
        for (int dp = 0; dp < 4; ++dp) {   // vf kc2=0, ds pairs (0,1)(2,3)(4,5)(6,7)
            const u8* ba = tv + (((dp * 2) * 32 + c31) * 4 + cswA) * 8;
            vfa[2 * dp] = *(const i64*)(ba);
            vfa[2 * dp + 1] = *(const i64*)(ba + 1024);
        }
        #pragma unroll
        for (int j = 0; j < 8; ++j) s = MFMA8(kf[j], qf[j], s);

        // ---- QK group 2 (kc 8..15) + vfb loads overlapped ----
        i64 vfb[8];
        #pragma unroll
        for (int m = 4; m < 8; ++m) {
            const int cl = ((2 * m) & 8) | (((2 * m) & 6) ^ (c31 & 6));
            const u8* ba = tk + kbase + cl * 16;
            kf[2 * (m - 4)] = *(const i64*)(ba);
            kf[2 * (m - 4) + 1] = *(const i64*)(ba + 16);
        }
        #pragma unroll
        for (int dp = 0; dp < 4; ++dp) {   // vf kc2=1
            const u8* ba = tv + (((dp * 2) * 32 + c31) * 4 + cswB) * 8;
            vfb[2 * dp] = *(const i64*)(ba);
            vfb[2 * dp + 1] = *(const i64*)(ba + 1024);
        }
        #pragma unroll
        for (int j = 0; j < 8; ++j) s = MFMA8(kf[j], qf[8 + j], s);

        // ---- phase A: exp first half -> A0 ----
        const float e0 = __expf(s[0]), e1 = __expf(s[1]), e2 = __expf(s[2]), e3 = __expf(s[3]);
        const float e4 = __expf(s[4]), e5 = __expf(s[5]), e6 = __expf(s[6]), e7 = __expf(s[7]);
        const u32 p0 = pk_fp8(e0, e1, e2, e3);
        const u32 p1 = pk_fp8(e4, e5, e6, e7);
        const u32 x0 = (u32)__shfl_xor((int)(g1 ? p0 : p1), 32, 64);
        const i64 A0 = g1 ? (i64)(((u64)p1 << 32) | x0) : (i64)(((u64)x0 << 32) | p0);

        // ---- phase B: PV kc2=0 MFMAs interleaved with exp second half -> A1 ----
        o[0] = MFMA8(A0, vfa[0], o[0]);
        const float e8 = __expf(s[8]), e9 = __expf(s[9]);
        o[1] = MFMA8(A0, vfa[1], o[1]);
        const float e10 = __expf(s[10]), e11 = __expf(s[11]);
        o[2] = MFMA8(A0, vfa[2], o[2]);
        const float e12 = __expf(s[12]), e13 = __expf(s[13]);
        o[3] = MFMA8(A0, vfa[3], o[3]);
        const float e14 = __expf(s[14]), e15 = __expf(s[15]);
        o[4] = MFMA8(A0, vfa[4], o[4]);
        const u32 p2 = pk_fp8(e8, e9, e10, e11);
        lsum += (e0 + e1) + (e2 + e3);
        o[5] = MFMA8(A0, vfa[5], o[5]);
        const u32 p3 = pk_fp8(e12, e13, e14, e15);
        lsum += (e4 + e5) + (e6 + e7);
        o[6] = MFMA8(A0, vfa[6], o[6]);
        const u32 x1 = (u32)__shfl_xor((int)(g1 ? p2 : p3), 32, 64);
        lsum += (e8 + e9) + (e10 + e11);
        o[7] = MFMA8(A0, vfa[7], o[7]);
        const i64 A1 = g1 ? (i64)(((u64)p3 << 32) | x1) : (i64)(((u64)x1 << 32) | p2);
        lsum += (e12 + e13) + (e14 + e15);

        // ---- phase C: PV kc2=1 ----
        #pragma unroll
        for (int ds = 0; ds < 8; ++ds) o[ds] = MFMA8(A1, vfb[ds], o[ds]);
    }

    // ---- epilogue: bf16 partial O + fp32 partial l ----
    u16* ob = Opart + ((size_t)split * BN + q0) * DIM;
    #pragma unroll
    for (int ds = 0; ds < 8; ++ds) {
        #pragma unroll
        for (int r = 0; r < 16; ++r) {
            const int ql = (r & 3) + 8 * (r >> 2) + 4 * g1;
            ob[(size_t)ql * DIM + ds * 32 + c31] = f2bf(o[ds][r]);
        }
    }
    lsum += __shfl_xor(lsum, 32, 64);
    if (g1 == 0) lpart[(size_t)split * BN + q0 + c31] = lsum;
}

// ---------------- kernel 3: merge splits, blend, final l2-normalize ----------------
__global__ __launch_bounds__(256) void k_combine(
        const float* __restrict__ feats, const u16* __restrict__ Opart,
        const float* __restrict__ lpart, float* __restrict__ out) {
    const int row = blockIdx.x * 4 + (threadIdx.x >> 6);
    const int lane = threadIdx.x & 63;

    float L = 0.f;
    #pragma unroll
    for (int s = 0; s < NSPLIT; ++s) L += lpart[(size_t)s * BN + row];

    float a0 = 0.f, a1 = 0.f, a2 = 0.f, a3 = 0.f;
    #pragma unroll
    for (int s = 0; s < NSPLIT; ++s) {
        const ushort4 o = *(const ushort4*)(Opart + ((size_t)s * BN + row) * DIM + lane * 4);
        a0 += bf2f(o.x); a1 += bf2f(o.y); a2 += bf2f(o.z); a3 += bf2f(o.w);
    }
    const float invL = 1.0f / L;

    const float4 v = *(const float4*)(feats + (size_t)row * DIM + lane * 4);
    float ss = v.x * v.x + v.y * v.y + v.z * v.z + v.w * v.w;
    #pragma unroll
    for (int off = 1; off < 64; off <<= 1) ss += __shfl_xor(ss, off, 64);
    const float invf = 1.0f / fmaxf(sqrtf(ss), 1e-12f);

    const float yx = 0.8f * v.x * invf + 0.2f * a0 * invL;
    const float yy = 0.8f * v.y * invf + 0.2f * a1 * invL;
    const float yz = 0.8f * v.z * invf + 0.2f * a2 * invL;
    const float yw = 0.8f * v.w * invf + 0.2f * a3 * invL;

    float s2 = yx * yx + yy * yy + yz * yz + yw * yw;
    #pragma unroll
    for (int off = 1; off < 64; off <<= 1) s2 += __shfl_xor(s2, off, 64);
    const float invn = 1.0f / fmaxf(sqrtf(s2), 1e-12f);

    float4 o; o.x = yx * invn; o.y = yy * invn; o.z = yz * invn; o.w = yw * invn;
    *(float4*)(out + (size_t)row * DIM + lane * 4) = o;
}

// ---------------- launcher ----------------
extern "C" void kernel_launch(void* const* d_in, const int* in_sizes, int n_in,
                              void* d_out, int out_size, void* d_ws, size_t ws_size,
                              hipStream_t stream) {
    const float* feats = (const float*)d_in[0];
    float* out = (float*)d_out;
    char* ws = (char*)d_ws;

    // ws: fb fp8 2MB | fv fp8 2MB | Opart bf16 32MB | lpart fp32 256KB
    u8* fb = (u8*)ws;
    u8* fv = (u8*)(ws + (size_t)BN * DIM);
    u16* Op = (u16*)(ws + (size_t)BN * DIM * 2);
    float* lp = (float*)(ws + (size_t)BN * DIM * 2 + (size_t)NSPLIT * BN * DIM * 2);

    k_prep<<<BN / 32, 256, 0, stream>>>(feats, fb, fv);
    k_flash<<<(BN / 128) * NSPLIT, 256, 0, stream>>>(fb, fv, Op, lp);
    k_combine<<<BN / 4, 256, 0, stream>>>(feats, Op, lp, out);
}